// Round 9
// baseline (251.670 us; speedup 1.0000x reference)
//
#include <hip/hip_runtime.h>
#include <hip/hip_bf16.h>
#include <math.h>

#define NQ 4096
#define CC 256

typedef __attribute__((ext_vector_type(8))) short bfrag;
typedef __attribute__((ext_vector_type(4))) float ffrag;

__device__ inline unsigned short f2bf(float x) {
  __hip_bfloat16 h = __float2bfloat16(x);
  return *reinterpret_cast<unsigned short*>(&h);
}

__device__ inline float bf2f(unsigned short u) {
  return __uint_as_float(((unsigned)u) << 16);
}

__device__ inline void gload16(const void* g, void* l) {
  __builtin_amdgcn_global_load_lds(
      (const __attribute__((address_space(1))) void*)g,
      (__attribute__((address_space(3))) void*)l, 16, 0, 0);
}

// ================================================================= prep mega
__device__ void tr64(const float* __restrict__ src,
                     unsigned short* __restrict__ dstb, int Cin, int P,
                     int p0, int c0, int b, float (*t)[73]) {
  int tid = threadIdx.x;
  int rx = tid & 15, ry = tid >> 4;
  const float* Sb = src + (size_t)b * Cin * P + p0 + rx * 4;
  #pragma unroll
  for (int i = 0; i < 4; i++) {
    int r = ry + i * 16;
    float4 v = *(const float4*)(Sb + (size_t)(c0 + r) * P);
    t[r][rx * 4 + 0] = v.x; t[r][rx * 4 + 1] = v.y;
    t[r][rx * 4 + 2] = v.z; t[r][rx * 4 + 3] = v.w;
  }
  __syncthreads();
  size_t ob = (size_t)b * P * Cin;
  #pragma unroll
  for (int i = 0; i < 4; i++) {
    int pr = ry + i * 16;
    float x0 = t[rx * 4 + 0][pr], x1 = t[rx * 4 + 1][pr];
    float x2 = t[rx * 4 + 2][pr], x3 = t[rx * 4 + 3][pr];
    size_t idx = ob + (size_t)(p0 + pr) * Cin + c0 + rx * 4;
    ushort4 u4;
    u4.x = f2bf(x0); u4.y = f2bf(x1); u4.z = f2bf(x2); u4.w = f2bf(x3);
    *(ushort4*)(dstb + idx) = u4;
  }
}

__global__ __launch_bounds__(256)
void prep_all_k(const float* S, const float* f0, const float* f1, const float* f2,
                const float* q_w, const float* off_w, const float* wgt_w,
                const float* vw0, const float* vw1, const float* vw2,
                const float* out_w, const float* fc1_w, const float* fc2_w,
                const float* off_b, const float* wgt_b,
                unsigned short* Sbf,
                unsigned short* Xf0, unsigned short* Xf1, unsigned short* Xf2,
                unsigned short* q_wb, unsigned short* owb,
                unsigned short* vw0b, unsigned short* vw1b, unsigned short* vw2b,
                unsigned short* out_wb, unsigned short* fc1_wb,
                unsigned short* fc2_wb, float* bias144) {
  __shared__ float t[64][73];
  int bid = blockIdx.x;
  if (bid < 512) {
    int l = bid;
    tr64(S, Sbf, 256, 4096, (l & 63) * 64, ((l >> 6) & 3) * 64, l >> 8, t);
  } else if (bid < 1024) {
    int l = bid - 512;
    tr64(f0, Xf0, 256, 4096, (l & 63) * 64, ((l >> 6) & 3) * 64, l >> 8, t);
  } else if (bid < 1280) {
    int l = bid - 1024;
    tr64(f1, Xf1, 512, 1024, (l & 15) * 64, ((l >> 4) & 7) * 64, l >> 7, t);
  } else if (bid < 1408) {
    int l = bid - 1280;
    tr64(f2, Xf2, 1024, 256, (l & 3) * 64, ((l >> 2) & 15) * 64, l >> 6, t);
  } else if (bid < 2688) {
    int i4 = (bid - 1408) * 256 + threadIdx.x;
    const float* src; unsigned short* dst;
    if (i4 < 16384)       { src = q_w;   dst = q_wb; }
    else if (i4 < 32768)  { i4 -= 16384;  src = vw0;   dst = vw0b; }
    else if (i4 < 65536)  { i4 -= 32768;  src = vw1;   dst = vw1b; }
    else if (i4 < 131072) { i4 -= 65536;  src = vw2;   dst = vw2b; }
    else if (i4 < 196608) { i4 -= 131072; src = out_w; dst = out_wb; }
    else if (i4 < 262144) { i4 -= 196608; src = fc1_w; dst = fc1_wb; }
    else                  { i4 -= 262144; src = fc2_w; dst = fc2_wb; }
    float4 v = ((const float4*)src)[i4];
    ushort4 u; u.x = f2bf(v.x); u.y = f2bf(v.y); u.z = f2bf(v.z); u.w = f2bf(v.w);
    ((ushort4*)dst)[i4] = u;
  } else {
    int e = (bid - 2688) * 256 + threadIdx.x;
    float v = (e < 24576) ? off_w[e] : (e < 36864 ? wgt_w[e - 24576] : 0.f);
    owb[e] = f2bf(v);
    if (e < 96) bias144[e] = off_b[e];
    else if (e < 144) bias144[e] = wgt_b[e - 96];
  }
}

// ================================================================= GEMM bodies
// Shared fragment-compute for one K-step (2 ks-halves) from LDS buffers.
template<int BM, int BN, int MI, int NI, int LBM, int LBN>
__device__ __forceinline__ void kstep_mfma(
    const unsigned short* Ab, const unsigned short* Bb, int quad, int l16,
    int mbase, int nbase, ffrag (&acc)[MI][NI]) {
  #pragma unroll
  for (int ks = 0; ks < 2; ks++) {
    bfrag af[MI], bf[NI];
    #pragma unroll
    for (int mi = 0; mi < MI; mi++)
      af[mi] = *(const bfrag*)(Ab + ((((ks * 4 + quad) << LBM) + mbase + mi * 16 + l16) << 3));
    #pragma unroll
    for (int ni = 0; ni < NI; ni++)
      bf[ni] = *(const bfrag*)(Bb + ((((ks * 4 + quad) << LBN) + nbase + ni * 16 + l16) << 3));
    #pragma unroll
    for (int mi = 0; mi < MI; mi++)
      #pragma unroll
      for (int ni = 0; ni < NI; ni++)
        acc[mi][ni] = __builtin_amdgcn_mfma_f32_16x16x32_bf16(
            af[mi], bf[ni], acc[mi][ni], 0, 0, 0);
  }
}

// EPI 0: fp32+bias  1: GELU->bf16  2: +bias+bf16 Zres, transposed fp32 store
//     3: bf16+bias  4: fp32 no bias (partial)
template<int BM, int BN, int WM, int WN, int EPI, int MI, int NI>
__device__ __forceinline__ void gemm_epilogue(
    ffrag (&acc)[MI][NI], const float* __restrict__ bias,
    float* __restrict__ outf, unsigned short* __restrict__ outb, int N,
    int ldo, const unsigned short* __restrict__ Zres, float* __restrict__ outT,
    int m0, int n0, int quad, int l16, int mbase, int nbase) {
  if (EPI == 2) {
    #pragma unroll
    for (int mi = 0; mi < MI; mi++) {
      int mrow = m0 + mbase + mi * 16 + quad * 4;
      int bb = mrow >> 12, q0 = mrow & (NQ - 1);
      #pragma unroll
      for (int ni = 0; ni < NI; ni++) {
        int n = n0 + nbase + ni * 16 + l16;
        float bv = bias[n];
        float4 v;
        v.x = acc[mi][ni][0] + bv + bf2f(Zres[(size_t)(mrow + 0) * CC + n]);
        v.y = acc[mi][ni][1] + bv + bf2f(Zres[(size_t)(mrow + 1) * CC + n]);
        v.z = acc[mi][ni][2] + bv + bf2f(Zres[(size_t)(mrow + 2) * CC + n]);
        v.w = acc[mi][ni][3] + bv + bf2f(Zres[(size_t)(mrow + 3) * CC + n]);
        *(float4*)(outT + ((size_t)(bb * CC + n)) * NQ + q0) = v;
      }
    }
  } else {
    #pragma unroll
    for (int mi = 0; mi < MI; mi++) {
      int mrow = m0 + mbase + mi * 16 + quad * 4;
      #pragma unroll
      for (int ni = 0; ni < NI; ni++) {
        int n = n0 + nbase + ni * 16 + l16;
        if (n < N) {
          float bv = (EPI == 4) ? 0.f : bias[n];
          #pragma unroll
          for (int r = 0; r < 4; r++) {
            float v = acc[mi][ni][r] + bv;
            if (EPI == 1) {
              v = 0.5f * v * (1.f + erff(v * 0.70710678118654752f));
              outb[(size_t)(mrow + r) * ldo + n] = f2bf(v);
            } else if (EPI == 3) {
              outb[(size_t)(mrow + r) * ldo + n] = f2bf(v);
            } else {
              outf[(size_t)(mrow + r) * ldo + n] = v;
            }
          }
        }
      }
    }
  }
}

// 3-stage pipeline: counted s_waitcnt vmcnt(LPW) + raw s_barrier keeps the
// newest stage's loads in flight ACROSS the barrier. Requires Kloop >= 128.
// LDS: 3*ATILE + 3*BTILE.
template<int BM, int BN, int WM, int WN, int EPI>
__device__ __forceinline__ void gemm_p3(
    const unsigned short* __restrict__ A, const unsigned short* __restrict__ B,
    const float* __restrict__ bias, float* __restrict__ outf,
    unsigned short* __restrict__ outb, int N, int Kloop, int lda, int ldb,
    int ldo, const unsigned short* __restrict__ Zres, float* __restrict__ outT,
    int m0, int n0, unsigned short* As, unsigned short* Bs) {
  constexpr int MI = BM / (WM * 16), NI = BN / (WN * 16);
  constexpr int TA = BM / 8, TB = BN / 8;
  constexpr int LBM = (BM == 32) ? 5 : (BM == 64) ? 6 : 7;
  constexpr int LBN = (BN == 64) ? 6 : (BN == 128) ? 7 : 8;
  constexpr int ATILE = TA * 1024, BTILE = TB * 1024;
  constexpr int LPW = (TA + TB) / 4;
  int tid = threadIdx.x, wave = tid >> 6, lane = tid & 63;
  int quad = lane >> 4, l16 = lane & 15;
  int wm = wave / WN, wn = wave % WN;
  const int mbase = wm * (BM / WM), nbase = wn * (BN / WN);

  ffrag acc[MI][NI];
  #pragma unroll
  for (int i = 0; i < MI; i++)
    #pragma unroll
    for (int j = 0; j < NI; j++) acc[i][j] = (ffrag)0.f;

  auto stage = [&](int kk, int st) {
    for (int t = wave; t < TA + TB; t += 4) {
      if (t < TA) {
        int s = t * 64 + lane;
        int kc = s >> LBM, r = s & (BM - 1);
        gload16(A + (size_t)(m0 + r) * lda + kk + kc * 8,
                (char*)As + st * ATILE + t * 1024);
      } else {
        int s = (t - TA) * 64 + lane;
        int kc = s >> LBN, r = s & (BN - 1);
        gload16(B + (size_t)(n0 + r) * ldb + kk + kc * 8,
                (char*)Bs + st * BTILE + (t - TA) * 1024);
      }
    }
  };

  stage(0, 0);
  stage(64, 1);
  asm volatile("s_waitcnt vmcnt(%0)" :: "n"(LPW) : "memory");
  __builtin_amdgcn_s_barrier();
  asm volatile("" ::: "memory");

  const int nsteps = Kloop >> 6;
  for (int i = 0; i < nsteps; i++) {
    int kn2 = (i + 2) << 6;
    if (kn2 < Kloop) stage(kn2, (i + 2) % 3);
    int bufo = i % 3;
    const unsigned short* Ab = (const unsigned short*)((const char*)As + bufo * ATILE);
    const unsigned short* Bb = (const unsigned short*)((const char*)Bs + bufo * BTILE);
    kstep_mfma<BM, BN, MI, NI, LBM, LBN>(Ab, Bb, quad, l16, mbase, nbase, acc);
    if (i + 1 < nsteps) {
      if (kn2 < Kloop)
        asm volatile("s_waitcnt vmcnt(%0)" :: "n"(LPW) : "memory");
      else
        asm volatile("s_waitcnt vmcnt(0)" ::: "memory");
      __builtin_amdgcn_s_barrier();
      asm volatile("" ::: "memory");
    }
  }
  gemm_epilogue<BM, BN, WM, WN, EPI, MI, NI>(acc, bias, outf, outb, N, ldo,
                                             Zres, outT, m0, n0, quad, l16,
                                             mbase, nbase);
}

// 2-stage dbuf (round-2/4 proven): stage(next) before compute(cur), one
// __syncthreads per K-step. LDS: 2*ATILE + 2*BTILE.
template<int BM, int BN, int WM, int WN, int EPI>
__device__ __forceinline__ void gemm_db2(
    const unsigned short* __restrict__ A, const unsigned short* __restrict__ B,
    const float* __restrict__ bias, float* __restrict__ outf,
    unsigned short* __restrict__ outb, int N, int Kloop, int lda, int ldb,
    int ldo, const unsigned short* __restrict__ Zres, float* __restrict__ outT,
    int m0, int n0, unsigned short* As, unsigned short* Bs) {
  constexpr int MI = BM / (WM * 16), NI = BN / (WN * 16);
  constexpr int TA = BM / 8, TB = BN / 8;
  constexpr int LBM = (BM == 32) ? 5 : (BM == 64) ? 6 : 7;
  constexpr int LBN = (BN == 64) ? 6 : (BN == 128) ? 7 : 8;
  constexpr int ATILE = TA * 1024, BTILE = TB * 1024;
  int tid = threadIdx.x, wave = tid >> 6, lane = tid & 63;
  int quad = lane >> 4, l16 = lane & 15;
  int wm = wave / WN, wn = wave % WN;
  const int mbase = wm * (BM / WM), nbase = wn * (BN / WN);

  ffrag acc[MI][NI];
  #pragma unroll
  for (int i = 0; i < MI; i++)
    #pragma unroll
    for (int j = 0; j < NI; j++) acc[i][j] = (ffrag)0.f;

  auto stage = [&](int kk, int st) {
    for (int t = wave; t < TA + TB; t += 4) {
      if (t < TA) {
        int s = t * 64 + lane;
        int kc = s >> LBM, r = s & (BM - 1);
        gload16(A + (size_t)(m0 + r) * lda + kk + kc * 8,
                (char*)As + st * ATILE + t * 1024);
      } else {
        int s = (t - TA) * 64 + lane;
        int kc = s >> LBN, r = s & (BN - 1);
        gload16(B + (size_t)(n0 + r) * ldb + kk + kc * 8,
                (char*)Bs + st * BTILE + (t - TA) * 1024);
      }
    }
  };

  stage(0, 0);
  __syncthreads();
  int buf = 0;
  for (int k0 = 0; k0 < Kloop; k0 += 64) {
    int kn = k0 + 64;
    if (kn < Kloop) stage(kn, buf ^ 1);
    const unsigned short* Ab = (const unsigned short*)((const char*)As + buf * ATILE);
    const unsigned short* Bb = (const unsigned short*)((const char*)Bs + buf * BTILE);
    kstep_mfma<BM, BN, MI, NI, LBM, LBN>(Ab, Bb, quad, l16, mbase, nbase, acc);
    __syncthreads();
    buf ^= 1;
  }
  gemm_epilogue<BM, BN, WM, WN, EPI, MI, NI>(acc, bias, outf, outb, N, ldo,
                                             Zres, outT, m0, n0, quad, l16,
                                             mbase, nbase);
}

// ================================================================= Q GEMM+LN
// BM=32, BN=256, BK=64 (proven config; single-buffered — LN needs full row)
__device__ __forceinline__ void gemm_ln_q(
    const unsigned short* __restrict__ A, const unsigned short* __restrict__ B,
    const float* __restrict__ bias, unsigned short* __restrict__ outb,
    const float* __restrict__ g, const float* __restrict__ be,
    int m0, char* sm) {
  unsigned short* As = (unsigned short*)sm;
  unsigned short* Bs = (unsigned short*)(sm + 4096);
  float* L = (float*)sm;
  const int K = 256;

  int tid = threadIdx.x, wave = tid >> 6, lane = tid & 63;
  int quad = lane >> 4, l16 = lane & 15;

  ffrag acc[2][4];
  #pragma unroll
  for (int i = 0; i < 2; i++)
    #pragma unroll
    for (int j = 0; j < 4; j++) acc[i][j] = (ffrag)0.f;

  for (int k0 = 0; k0 < K; k0 += 64) {
    __syncthreads();
    for (int t = wave; t < 36; t += 4) {
      if (t < 4) {
        int s = t * 64 + lane;
        int kc = s >> 5, r = s & 31;
        gload16(A + (size_t)(m0 + r) * K + k0 + kc * 8, sm + t * 1024);
      } else {
        int s = (t - 4) * 64 + lane;
        int kc = s >> 8, r = s & 255;
        gload16(B + (size_t)r * K + k0 + kc * 8, sm + 4096 + (t - 4) * 1024);
      }
    }
    __syncthreads();
    #pragma unroll
    for (int ks = 0; ks < 2; ks++) {
      bfrag af[2], bf[4];
      #pragma unroll
      for (int mi = 0; mi < 2; mi++)
        af[mi] = *(const bfrag*)(As + ((((ks * 4 + quad) << 5) + mi * 16 + l16) << 3));
      #pragma unroll
      for (int ni = 0; ni < 4; ni++)
        bf[ni] = *(const bfrag*)(Bs + ((((ks * 4 + quad) << 8) + wave * 64 + ni * 16 + l16) << 3));
      #pragma unroll
      for (int mi = 0; mi < 2; mi++)
        #pragma unroll
        for (int ni = 0; ni < 4; ni++)
          acc[mi][ni] = __builtin_amdgcn_mfma_f32_16x16x32_bf16(
              af[mi], bf[ni], acc[mi][ni], 0, 0, 0);
    }
  }
  __syncthreads();

  #pragma unroll
  for (int mi = 0; mi < 2; mi++) {
    int row = mi * 16 + quad * 4;
    #pragma unroll
    for (int ni = 0; ni < 4; ni++) {
      int col = wave * 64 + ni * 16 + l16;
      float bv = bias[col];
      #pragma unroll
      for (int r = 0; r < 4; r++)
        L[(row + r) * 264 + col] = acc[mi][ni][r] + bv;
    }
  }
  __syncthreads();

  int row = tid >> 3, j = tid & 7;
  int seg = ((j + row) & 7) * 32;
  const float* Lr = L + row * 264 + seg;
  float s1 = 0.f, s2 = 0.f;
  #pragma unroll
  for (int i = 0; i < 8; i++) {
    float4 t4 = *(const float4*)(Lr + i * 4);
    s1 += t4.x + t4.y + t4.z + t4.w;
    s2 += t4.x * t4.x + t4.y * t4.y + t4.z * t4.z + t4.w * t4.w;
  }
  #pragma unroll
  for (int o = 1; o < 8; o <<= 1) {
    s1 += __shfl_xor(s1, o);
    s2 += __shfl_xor(s2, o);
  }
  float mu = s1 * (1.f / 256.f);
  float var = s2 * (1.f / 256.f) - mu * mu;
  float rs = rsqrtf(var + 1e-5f);
  int gm = m0 + row;
  #pragma unroll
  for (int i = 0; i < 8; i++) {
    int col = seg + i * 4;
    float4 t4 = *(const float4*)(Lr + i * 4);
    float4 gg = *(const float4*)(g + col);
    float4 bb4 = *(const float4*)(be + col);
    ushort4 ub;
    ub.x = f2bf((t4.x - mu) * rs * gg.x + bb4.x);
    ub.y = f2bf((t4.y - mu) * rs * gg.y + bb4.y);
    ub.z = f2bf((t4.z - mu) * rs * gg.z + bb4.z);
    ub.w = f2bf((t4.w - mu) * rs * gg.w + bb4.w);
    *(ushort4*)(outb + (size_t)gm * CC + col) = ub;
  }
}

// ================================================================= kernels
// qv: [0,256) Q-LN | [256,512) V0 p3 | [512,640) V1 split2 p3
//     [640,704) V2 split4 p3 — m-fastest tile order (XCD-disjoint A-slabs)
__global__ __launch_bounds__(256)
void qv_k(const unsigned short* Sbf, const unsigned short* q_wb, const float* q_b,
          const float* lnq_g, const float* lnq_b, unsigned short* Qbf,
          const unsigned short* Xf0, const unsigned short* Xf1,
          const unsigned short* Xf2, const unsigned short* vw0b,
          const unsigned short* vw1b, const unsigned short* vw2b,
          const float* vb0, unsigned short* V0b, float* Vp1, float* Vp2) {
  __shared__ __attribute__((aligned(16))) char sm[73728];
  int bid = blockIdx.x;
  unsigned short* As = (unsigned short*)sm;
  unsigned short* Bs = (unsigned short*)(sm + 24576);
  if (bid < 256) {
    gemm_ln_q(Sbf, q_wb, q_b, Qbf, lnq_g, lnq_b, bid * 32, sm);
  } else if (bid < 512) {
    int t = bid - 256;
    gemm_p3<64, 128, 2, 2, 3>(Xf0, vw0b, vb0, nullptr, V0b, 256, 256, 256,
                              256, 256, nullptr, nullptr,
                              (t & 127) * 64, (t >> 7) * 128, As, Bs);
  } else if (bid < 640) {
    int l = bid - 512, ks = l >> 6, t = l & 63;
    gemm_p3<64, 128, 2, 2, 4>(Xf1 + ks * 256, vw1b + ks * 256, nullptr,
                              Vp1 + (size_t)ks * 524288, nullptr, 256, 256,
                              512, 512, 256, nullptr, nullptr,
                              (t & 31) * 64, (t >> 5) * 128, As, Bs);
  } else {
    int l = bid - 640, ks = l >> 4, t = l & 15;
    gemm_p3<64, 128, 2, 2, 4>(Xf2 + ks * 256, vw2b + ks * 256, nullptr,
                              Vp2 + (size_t)ks * 131072, nullptr, 256, 256,
                              1024, 1024, 256, nullptr, nullptr,
                              (t & 7) * 64, (t >> 3) * 128, As, Bs);
  }
}

// offv: [0,256) offwgt GEMM 64x128 p3, m-fastest | [256,768) V1 red | [768,896) V2 red
__global__ __launch_bounds__(256)
void offv_k(const unsigned short* Qbf, const unsigned short* owb,
            const float* bias144, float* offwgt,
            const float* Vp1, const float* Vp2, const float* vb1,
            const float* vb2, unsigned short* V1b, unsigned short* V2b) {
  __shared__ __attribute__((aligned(16))) char sm[73728];
  int bid = blockIdx.x;
  if (bid < 256) {
    unsigned short* As = (unsigned short*)sm;
    unsigned short* Bs = (unsigned short*)(sm + 24576);
    gemm_p3<64, 128, 2, 2, 0>(Qbf, owb, bias144, offwgt, nullptr, 144, 256,
                              256, 256, 144, nullptr, nullptr,
                              (bid & 127) * 64, (bid >> 7) * 128, As, Bs);
  } else if (bid < 768) {
    int e4 = (bid - 256) * 256 + threadIdx.x;
    const float4* P = (const float4*)Vp1;
    float4 a = P[e4], b = P[e4 + 131072];
    float4 bb = *(const float4*)(vb1 + ((e4 << 2) & 255));
    ushort4 u;
    u.x = f2bf(a.x + b.x + bb.x); u.y = f2bf(a.y + b.y + bb.y);
    u.z = f2bf(a.z + b.z + bb.z); u.w = f2bf(a.w + b.w + bb.w);
    ((ushort4*)V1b)[e4] = u;
  } else {
    int e4 = (bid - 768) * 256 + threadIdx.x;
    const float4* P = (const float4*)Vp2;
    float4 a = P[e4], b = P[e4 + 32768], c = P[e4 + 65536], d = P[e4 + 98304];
    float4 bb = *(const float4*)(vb2 + ((e4 << 2) & 255));
    ushort4 u;
    u.x = f2bf(a.x + b.x + c.x + d.x + bb.x);
    u.y = f2bf(a.y + b.y + c.y + d.y + bb.y);
    u.z = f2bf(a.z + b.z + c.z + d.z + bb.z);
    u.w = f2bf(a.w + b.w + c.w + d.w + bb.w);
    ((ushort4*)V2b)[e4] = u;
  }
}

// outAB2: fused out-projection + residual + LN. BM=32, BN=256 (full row),
// full K=1024, 2-stage dbuf (2x36KB, round-6-verified schedule). Epilogue:
// +out_b, +S residual (transposed float4 read, outB's proven pattern),
// row-LN -> Zbf bf16. Kills the 32 MB Pp round-trip and the outB kernel.
__global__ __launch_bounds__(256)
void outAB2_k(const unsigned short* __restrict__ A,
              const unsigned short* __restrict__ Bw,
              const float* __restrict__ out_b, const float* __restrict__ S,
              const float* __restrict__ g, const float* __restrict__ be,
              unsigned short* __restrict__ Zbf) {
  __shared__ __attribute__((aligned(16))) char sm[73728];
  float* L = (float*)sm;
  const int K = 1024;
  int m0 = blockIdx.x * 32;
  int tid = threadIdx.x, wave = tid >> 6, lane = tid & 63;
  int quad = lane >> 4, l16 = lane & 15;

  ffrag acc[2][4];
  #pragma unroll
  for (int i = 0; i < 2; i++)
    #pragma unroll
    for (int j = 0; j < 4; j++) acc[i][j] = (ffrag)0.f;

  auto stageq = [&](int k0, int st) {
    char* base = sm + st * 36864;
    for (int t = wave; t < 36; t += 4) {
      if (t < 4) {
        int s = t * 64 + lane;
        int kc = s >> 5, r = s & 31;
        gload16(A + (size_t)(m0 + r) * K + k0 + kc * 8, base + t * 1024);
      } else {
        int s = (t - 4) * 64 + lane;
        int kc = s >> 8, r = s & 255;
        gload16(Bw + (size_t)r * K + k0 + kc * 8, base + 4096 + (t - 4) * 1024);
      }
    }
  };

  stageq(0, 0);
  __syncthreads();
  for (int i = 0; i < 16; i++) {
    if (i < 15) stageq((i + 1) * 64, (i + 1) & 1);
    const unsigned short* As = (const unsigned short*)(sm + (i & 1) * 36864);
    const unsigned short* Bs = As + 2048;
    #pragma unroll
    for (int ks = 0; ks < 2; ks++) {
      bfrag af[2], bf[4];
      #pragma unroll
      for (int mi = 0; mi < 2; mi++)
        af[mi] = *(const bfrag*)(As + ((((ks * 4 + quad) << 5) + mi * 16 + l16) << 3));
      #pragma unroll
      for (int ni = 0; ni < 4; ni++)
        bf[ni] = *(const bfrag*)(Bs + ((((ks * 4 + quad) << 8) + wave * 64 + ni * 16 + l16) << 3));
      #pragma unroll
      for (int mi = 0; mi < 2; mi++)
        #pragma unroll
        for (int ni = 0; ni < 4; ni++)
          acc[mi][ni] = __builtin_amdgcn_mfma_f32_16x16x32_bf16(
              af[mi], bf[ni], acc[mi][ni], 0, 0, 0);
    }
    __syncthreads();
  }

  // acc + out_b -> L
  #pragma unroll
  for (int mi = 0; mi < 2; mi++) {
    int row = mi * 16 + quad * 4;
    #pragma unroll
    for (int ni = 0; ni < 4; ni++) {
      int col = wave * 64 + ni * 16 + l16;
      float bv = out_b[col];
      #pragma unroll
      for (int r = 0; r < 4; r++)
        L[(row + r) * 264 + col] = acc[mi][ni][r] + bv;
    }
  }
  __syncthreads();

  // + S residual (transposed float4 read along q)
  int b = m0 >> 12, qq = m0 & (NQ - 1);
  {
    int cs = tid >> 3, j = (tid & 7) * 4;
    #pragma unroll
    for (int c0 = 0; c0 < 256; c0 += 32) {
      float4 sv = *(const float4*)(S + (((size_t)(b * 256 + c0 + cs)) << 12) + qq + j);
      L[(j + 0) * 264 + c0 + cs] += sv.x;
      L[(j + 1) * 264 + c0 + cs] += sv.y;
      L[(j + 2) * 264 + c0 + cs] += sv.z;
      L[(j + 3) * 264 + c0 + cs] += sv.w;
    }
  }
  __syncthreads();

  // row LN (32 rows, 8 threads/row)
  int row = tid >> 3, j = tid & 7;
  int seg = ((j + row) & 7) * 32;
  const float* Lr = L + row * 264 + seg;
  float s1 = 0.f, s2 = 0.f;
  #pragma unroll
  for (int i = 0; i < 8; i++) {
    float4 t4 = *(const float4*)(Lr + i * 4);
    s1 += t4.x + t4.y + t4.z + t4.w;
    s2 += t4.x * t4.x + t4.y * t4.y + t4.z * t4.z + t4.w * t4.w;
  }
  #pragma unroll
  for (int o = 1; o < 8; o <<= 1) {
    s1 += __shfl_xor(s1, o);
    s2 += __shfl_xor(s2, o);
  }
  float mu = s1 * (1.f / 256.f);
  float var = s2 * (1.f / 256.f) - mu * mu;
  float rs = rsqrtf(var + 1e-5f);
  int gm = m0 + row;
  #pragma unroll
  for (int i = 0; i < 8; i++) {
    int col = seg + i * 4;
    float4 t4 = *(const float4*)(Lr + i * 4);
    float4 gg = *(const float4*)(g + col);
    float4 bb4 = *(const float4*)(be + col);
    ushort4 ub;
    ub.x = f2bf((t4.x - mu) * rs * gg.x + bb4.x);
    ub.y = f2bf((t4.y - mu) * rs * gg.y + bb4.y);
    ub.z = f2bf((t4.z - mu) * rs * gg.z + bb4.z);
    ub.w = f2bf((t4.w - mu) * rs * gg.w + bb4.w);
    *(ushort4*)(Zbf + (size_t)gm * CC + col) = ub;
  }
}

// fc1: 128x128 db2 tiles (2:1 MFMA:ds_read), grid (m=64, n=8) m-fastest
__global__ __launch_bounds__(256)
void fc1_k(const unsigned short* Zbf, const unsigned short* fc1_wb,
           const float* fc1_b, unsigned short* hbf) {
  __shared__ __attribute__((aligned(16))) char sm[65536];
  gemm_db2<128, 128, 2, 2, 1>(Zbf, fc1_wb, fc1_b, nullptr, hbf, 1024, 256,
                              256, 256, 1024, nullptr, nullptr,
                              blockIdx.x * 128, blockIdx.y * 128,
                              (unsigned short*)sm, (unsigned short*)(sm + 32768));
}

// fc2: full-K=1024, 64x64 p3 tile, grid (m=128, n=4) m-fastest
__global__ __launch_bounds__(256)
void fc2_k(const unsigned short* hbf, const unsigned short* fc2_wb,
           const float* fc2_b, const unsigned short* Zbf, float* outp) {
  __shared__ __attribute__((aligned(16))) char sm[49152];
  gemm_p3<64, 64, 2, 2, 2>(hbf, fc2_wb, fc2_b, nullptr, nullptr, 256, 1024,
                           1024, 1024, 256, Zbf, outp,
                           blockIdx.x * 64, blockIdx.y * 64,
                           (unsigned short*)sm, (unsigned short*)(sm + 24576));
}

// ================================================================= sampling
__global__ __launch_bounds__(256)
void sample_k(const float* __restrict__ ow, const float* __restrict__ sim,
              const unsigned short* __restrict__ V0, const unsigned short* __restrict__ V1,
              const unsigned short* __restrict__ V2, unsigned short* __restrict__ acc) {
  int bn = blockIdx.x;
  int q = ((bn & 7) << 10) | (bn >> 3);
  int b = q >> 12, n = q & (NQ - 1);
  int tid = threadIdx.x, head = tid >> 6, lane = tid & 63;
  int half = lane >> 5, l32 = lane & 31;

  __shared__ float s_w[48];
  __shared__ int   s_xy[48][2];
  __shared__ float s_f[48][2];
  __shared__ uint2 s_ow[192];

  if (tid < 48) {
    int hh = tid / 12, pt = tid % 12, l = pt >> 2, mm = pt & 3;
    int oidx = (hh * 3 + l) * 4 + mm;
    float offx = ow[(size_t)q * 144 + oidx * 2 + 0];
    float offy = ow[(size_t)q * 144 + oidx * 2 + 1];
    float refx = ((n & 63) + 0.5f) * (1.f / 64.f);
    float refy = ((n >> 6) + 0.5f) * (1.f / 64.f);
    float gx = tanhf((refx + offx) * 2.f - 1.f);
    float gy = tanhf((refy + offy) * 2.f - 1.f);
    gx = fminf(1.f, fmaxf(-1.f, gx));
    gy = fminf(1.f, fmaxf(-1.f, gy));
    int Wl = 64 >> l;
    float x = (gx + 1.f) * 0.5f * (float)(Wl - 1);
    float y = (gy + 1.f) * 0.5f * (float)(Wl - 1);
    float x0 = floorf(x), y0 = floorf(y);
    s_xy[tid][0] = (int)x0;
    s_xy[tid][1] = (int)y0;
    s_f[tid][0] = x - x0;
    s_f[tid][1] = y - y0;
    s_w[tid] = ow[(size_t)q * 144 + 96 + oidx] * (sim[q] + 0.001f);
  }
  __syncthreads();
  if (tid < 4) {
    float mx = -1e30f;
    #pragma unroll
    for (int i = 0; i < 12; i++) mx = fmaxf(mx, s_w[tid * 12 + i]);
    float e[12], ssum = 0.f;
    #pragma unroll
    for (int i = 0; i < 12; i++) { e[i] = expf(s_w[tid * 12 + i] - mx); ssum += e[i]; }
    float inv = 1.f / ssum;
    #pragma unroll
    for (int i = 0; i < 12; i++) s_w[tid * 12 + i] = e[i] * inv;
  }
  __syncthreads();
  if (tid < 192) {
    int s = tid >> 2, tap = tid & 3;
    int l = (s % 12) >> 2;
    int Wl = 64 >> l;
    int X = s_xy[s][0] + (tap & 1), Y = s_xy[s][1] + (tap >> 1);
    bool valid = (X >= 0 && X < Wl && Y >= 0 && Y < Wl);
    float wx = (tap & 1) ? s_f[s][0] : 1.f - s_f[s][0];
    float wy = (tap >> 1) ? s_f[s][1] : 1.f - s_f[s][1];
    float twt = valid ? s_w[s] * wx * wy : 0.f;
    int Xc = min(max(X, 0), Wl - 1), Yc = min(max(Y, 0), Wl - 1);
    s_ow[tid].x = (unsigned)((Yc * Wl + Xc) << 8);
    s_ow[tid].y = __float_as_uint(twt);
  }
  __syncthreads();

  const unsigned short* B0 = V0 + (size_t)b * 4096 * CC;
  const unsigned short* B1 = V1 + (size_t)b * 1024 * CC;
  const unsigned short* B2 = V2 + (size_t)b * 256 * CC;
  int ch8 = l32 * 8;
  float a0 = 0.f, a1 = 0.f, a2 = 0.f, a3 = 0.f;
  float a4 = 0.f, a5 = 0.f, a6 = 0.f, a7 = 0.f;
  #pragma unroll
  for (int it = 0; it < 24; it++) {
    const unsigned short* base = (it < 8) ? B0 : (it < 16) ? B1 : B2;
    uint2 owv = s_ow[head * 48 + it * 2 + half];
    float w = __uint_as_float(owv.y);
    const uint4 u = *(const uint4*)(base + owv.x + ch8);
    a0 = fmaf(w, __uint_as_float(u.x << 16), a0);
    a1 = fmaf(w, __uint_as_float(u.x & 0xffff0000u), a1);
    a2 = fmaf(w, __uint_as_float(u.y << 16), a2);
    a3 = fmaf(w, __uint_as_float(u.y & 0xffff0000u), a3);
    a4 = fmaf(w, __uint_as_float(u.z << 16), a4);
    a5 = fmaf(w, __uint_as_float(u.z & 0xffff0000u), a5);
    a6 = fmaf(w, __uint_as_float(u.w << 16), a6);
    a7 = fmaf(w, __uint_as_float(u.w & 0xffff0000u), a7);
  }
  a0 += __shfl_xor(a0, 32); a1 += __shfl_xor(a1, 32);
  a2 += __shfl_xor(a2, 32); a3 += __shfl_xor(a3, 32);
  a4 += __shfl_xor(a4, 32); a5 += __shfl_xor(a5, 32);
  a6 += __shfl_xor(a6, 32); a7 += __shfl_xor(a7, 32);
  if (half == 0) {
    uint4 r;
    r.x = (unsigned)f2bf(a0) | ((unsigned)f2bf(a1) << 16);
    r.y = (unsigned)f2bf(a2) | ((unsigned)f2bf(a3) << 16);
    r.z = (unsigned)f2bf(a4) | ((unsigned)f2bf(a5) << 16);
    r.w = (unsigned)f2bf(a6) | ((unsigned)f2bf(a7) << 16);
    *(uint4*)(acc + (size_t)q * 1024 + head * CC + ch8) = r;
  }
}

// ================================================================= launch
extern "C" void kernel_launch(void* const* d_in, const int* in_sizes, int n_in,
                              void* d_out, int out_size, void* d_ws, size_t ws_size,
                              hipStream_t stream) {
  const float* S     = (const float*)d_in[0];
  const float* f0    = (const float*)d_in[1];
  const float* f1    = (const float*)d_in[2];
  const float* f2    = (const float*)d_in[3];
  const float* sim   = (const float*)d_in[4];
  const float* vw0   = (const float*)d_in[5];
  const float* vb0   = (const float*)d_in[6];
  const float* vw1   = (const float*)d_in[7];
  const float* vb1   = (const float*)d_in[8];
  const float* vw2   = (const float*)d_in[9];
  const float* vb2   = (const float*)d_in[10];
  const float* q_w   = (const float*)d_in[11];
  const float* q_b   = (const float*)d_in[12];
  const float* off_w = (const float*)d_in[13];
  const float* off_b = (const float*)d_in[14];
  const float* wgt_w = (const float*)d_in[15];
  const float* wgt_b = (const float*)d_in[16];
  const float* out_w = (const float*)d_in[17];
  const float* out_b = (const float*)d_in[18];
  const float* lnq_g = (const float*)d_in[19];
  const float* lnq_b = (const float*)d_in[20];
  const float* lno_g = (const float*)d_in[21];
  const float* lno_b = (const float*)d_in[22];
  const float* fc1_w = (const float*)d_in[23];
  const float* fc1_b = (const float*)d_in[24];
  const float* fc2_w = (const float*)d_in[25];
  const float* fc2_b = (const float*)d_in[26];

  char* p = (char*)d_ws;
  float* offwgt = (float*)p; p += 4718592;
  float* bias144 = (float*)p; p += 1024;
  float* Pp     = (float*)p; p += 16777216;   // unused (kept for layout)
  float* Vp1    = (float*)p; p += 4194304;
  float* Vp2    = (float*)p; p += 2097152;
  unsigned short* Sbf   = (unsigned short*)p; p += 4194304;
  unsigned short* Qbf   = (unsigned short*)p; p += 4194304;   // alias Zbf
  unsigned short* accbf = (unsigned short*)p; p += 16777216;  // alias Xf*, hbf
  unsigned short* V0b   = (unsigned short*)p; p += 4194304;
  unsigned short* V1b   = (unsigned short*)p; p += 1048576;
  unsigned short* V2b   = (unsigned short*)p; p += 262144;
  unsigned short* q_wb   = (unsigned short*)p; p += 131072;
  unsigned short* owb    = (unsigned short*)p; p += 131072;
  unsigned short* vw0b   = (unsigned short*)p; p += 131072;
  unsigned short* vw1b   = (unsigned short*)p; p += 262144;
  unsigned short* vw2b   = (unsigned short*)p; p += 524288;
  unsigned short* out_wb = (unsigned short*)p; p += 524288;
  unsigned short* fc1_wb = (unsigned short*)p; p += 524288;
  unsigned short* fc2_wb = (unsigned short*)p; p += 524288;

  unsigned short* Xf0 = accbf;
  unsigned short* Xf1 = accbf + 2097152;
  unsigned short* Xf2 = accbf + 3145728;
  unsigned short* Zbf = Qbf;
  unsigned short* hbf = accbf;
  float* outp = (float*)d_out;
  (void)Pp;

  prep_all_k<<<2944, 256, 0, stream>>>(S, f0, f1, f2, q_w, off_w, wgt_w,
      vw0, vw1, vw2, out_w, fc1_w, fc2_w, off_b, wgt_b,
      Sbf, Xf0, Xf1, Xf2, q_wb, owb, vw0b, vw1b, vw2b, out_wb,
      fc1_wb, fc2_wb, bias144);

  qv_k<<<704, 256, 0, stream>>>(Sbf, q_wb, q_b, lnq_g, lnq_b, Qbf,
      Xf0, Xf1, Xf2, vw0b, vw1b, vw2b, vb0, V0b, Vp1, Vp2);

  offv_k<<<896, 256, 0, stream>>>(Qbf, owb, bias144, offwgt,
      Vp1, Vp2, vb1, vb2, V1b, V2b);

  sample_k<<<8192, 256, 0, stream>>>(offwgt, sim, V0b, V1b, V2b, accbf);

  outAB2_k<<<256, 256, 0, stream>>>(accbf, out_wb, out_b, S, lno_g, lno_b, Zbf);

  fc1_k<<<dim3(64, 8), 256, 0, stream>>>(Zbf, fc1_wb, fc1_b, hbf);

  fc2_k<<<dim3(128, 4), 256, 0, stream>>>(hbf, fc2_wb, fc2_b, Zbf, outp);
}

// Round 10
// 242.614 us; speedup vs baseline: 1.0373x; 1.0373x over previous
//
#include <hip/hip_runtime.h>
#include <hip/hip_bf16.h>
#include <math.h>

#define NQ 4096
#define CC 256

typedef __attribute__((ext_vector_type(8))) short bfrag;
typedef __attribute__((ext_vector_type(4))) float ffrag;

__device__ inline unsigned short f2bf(float x) {
  __hip_bfloat16 h = __float2bfloat16(x);
  return *reinterpret_cast<unsigned short*>(&h);
}

__device__ inline float bf2f(unsigned short u) {
  return __uint_as_float(((unsigned)u) << 16);
}

__device__ inline void gload16(const void* g, void* l) {
  __builtin_amdgcn_global_load_lds(
      (const __attribute__((address_space(1))) void*)g,
      (__attribute__((address_space(3))) void*)l, 16, 0, 0);
}

// ================================================================= prep mega
__device__ void tr64(const float* __restrict__ src,
                     unsigned short* __restrict__ dstb, int Cin, int P,
                     int p0, int c0, int b, float (*t)[73]) {
  int tid = threadIdx.x;
  int rx = tid & 15, ry = tid >> 4;
  const float* Sb = src + (size_t)b * Cin * P + p0 + rx * 4;
  #pragma unroll
  for (int i = 0; i < 4; i++) {
    int r = ry + i * 16;
    float4 v = *(const float4*)(Sb + (size_t)(c0 + r) * P);
    t[r][rx * 4 + 0] = v.x; t[r][rx * 4 + 1] = v.y;
    t[r][rx * 4 + 2] = v.z; t[r][rx * 4 + 3] = v.w;
  }
  __syncthreads();
  size_t ob = (size_t)b * P * Cin;
  #pragma unroll
  for (int i = 0; i < 4; i++) {
    int pr = ry + i * 16;
    float x0 = t[rx * 4 + 0][pr], x1 = t[rx * 4 + 1][pr];
    float x2 = t[rx * 4 + 2][pr], x3 = t[rx * 4 + 3][pr];
    size_t idx = ob + (size_t)(p0 + pr) * Cin + c0 + rx * 4;
    ushort4 u4;
    u4.x = f2bf(x0); u4.y = f2bf(x1); u4.z = f2bf(x2); u4.w = f2bf(x3);
    *(ushort4*)(dstb + idx) = u4;
  }
}

__global__ __launch_bounds__(256)
void prep_all_k(const float* S, const float* f0, const float* f1, const float* f2,
                const float* q_w, const float* off_w, const float* wgt_w,
                const float* vw0, const float* vw1, const float* vw2,
                const float* out_w, const float* fc1_w, const float* fc2_w,
                const float* off_b, const float* wgt_b,
                unsigned short* Sbf,
                unsigned short* Xf0, unsigned short* Xf1, unsigned short* Xf2,
                unsigned short* q_wb, unsigned short* owb,
                unsigned short* vw0b, unsigned short* vw1b, unsigned short* vw2b,
                unsigned short* out_wb, unsigned short* fc1_wb,
                unsigned short* fc2_wb, float* bias144) {
  __shared__ float t[64][73];
  int bid = blockIdx.x;
  if (bid < 512) {
    int l = bid;
    tr64(S, Sbf, 256, 4096, (l & 63) * 64, ((l >> 6) & 3) * 64, l >> 8, t);
  } else if (bid < 1024) {
    int l = bid - 512;
    tr64(f0, Xf0, 256, 4096, (l & 63) * 64, ((l >> 6) & 3) * 64, l >> 8, t);
  } else if (bid < 1280) {
    int l = bid - 1024;
    tr64(f1, Xf1, 512, 1024, (l & 15) * 64, ((l >> 4) & 7) * 64, l >> 7, t);
  } else if (bid < 1408) {
    int l = bid - 1280;
    tr64(f2, Xf2, 1024, 256, (l & 3) * 64, ((l >> 2) & 15) * 64, l >> 6, t);
  } else if (bid < 2688) {
    int i4 = (bid - 1408) * 256 + threadIdx.x;
    const float* src; unsigned short* dst;
    if (i4 < 16384)       { src = q_w;   dst = q_wb; }
    else if (i4 < 32768)  { i4 -= 16384;  src = vw0;   dst = vw0b; }
    else if (i4 < 65536)  { i4 -= 32768;  src = vw1;   dst = vw1b; }
    else if (i4 < 131072) { i4 -= 65536;  src = vw2;   dst = vw2b; }
    else if (i4 < 196608) { i4 -= 131072; src = out_w; dst = out_wb; }
    else if (i4 < 262144) { i4 -= 196608; src = fc1_w; dst = fc1_wb; }
    else                  { i4 -= 262144; src = fc2_w; dst = fc2_wb; }
    float4 v = ((const float4*)src)[i4];
    ushort4 u; u.x = f2bf(v.x); u.y = f2bf(v.y); u.z = f2bf(v.z); u.w = f2bf(v.w);
    ((ushort4*)dst)[i4] = u;
  } else {
    int e = (bid - 2688) * 256 + threadIdx.x;
    float v = (e < 24576) ? off_w[e] : (e < 36864 ? wgt_w[e - 24576] : 0.f);
    owb[e] = f2bf(v);
    if (e < 96) bias144[e] = off_b[e];
    else if (e < 144) bias144[e] = wgt_b[e - 96];
  }
}

// ================================================================= GEMM bodies
// Shared fragment-compute for one K-step (2 ks-halves) from LDS buffers.
template<int BM, int BN, int MI, int NI, int LBM, int LBN>
__device__ __forceinline__ void kstep_mfma(
    const unsigned short* Ab, const unsigned short* Bb, int quad, int l16,
    int mbase, int nbase, ffrag (&acc)[MI][NI]) {
  #pragma unroll
  for (int ks = 0; ks < 2; ks++) {
    bfrag af[MI], bf[NI];
    #pragma unroll
    for (int mi = 0; mi < MI; mi++)
      af[mi] = *(const bfrag*)(Ab + ((((ks * 4 + quad) << LBM) + mbase + mi * 16 + l16) << 3));
    #pragma unroll
    for (int ni = 0; ni < NI; ni++)
      bf[ni] = *(const bfrag*)(Bb + ((((ks * 4 + quad) << LBN) + nbase + ni * 16 + l16) << 3));
    #pragma unroll
    for (int mi = 0; mi < MI; mi++)
      #pragma unroll
      for (int ni = 0; ni < NI; ni++)
        acc[mi][ni] = __builtin_amdgcn_mfma_f32_16x16x32_bf16(
            af[mi], bf[ni], acc[mi][ni], 0, 0, 0);
  }
}

// EPI 0: fp32+bias  1: GELU->bf16  2: +bias+bf16 Zres, transposed fp32 store
//     3: bf16+bias  4: fp32 no bias (partial)
template<int BM, int BN, int WM, int WN, int EPI, int MI, int NI>
__device__ __forceinline__ void gemm_epilogue(
    ffrag (&acc)[MI][NI], const float* __restrict__ bias,
    float* __restrict__ outf, unsigned short* __restrict__ outb, int N,
    int ldo, const unsigned short* __restrict__ Zres, float* __restrict__ outT,
    int m0, int n0, int quad, int l16, int mbase, int nbase) {
  if (EPI == 2) {
    #pragma unroll
    for (int mi = 0; mi < MI; mi++) {
      int mrow = m0 + mbase + mi * 16 + quad * 4;
      int bb = mrow >> 12, q0 = mrow & (NQ - 1);
      #pragma unroll
      for (int ni = 0; ni < NI; ni++) {
        int n = n0 + nbase + ni * 16 + l16;
        float bv = bias[n];
        float4 v;
        v.x = acc[mi][ni][0] + bv + bf2f(Zres[(size_t)(mrow + 0) * CC + n]);
        v.y = acc[mi][ni][1] + bv + bf2f(Zres[(size_t)(mrow + 1) * CC + n]);
        v.z = acc[mi][ni][2] + bv + bf2f(Zres[(size_t)(mrow + 2) * CC + n]);
        v.w = acc[mi][ni][3] + bv + bf2f(Zres[(size_t)(mrow + 3) * CC + n]);
        *(float4*)(outT + ((size_t)(bb * CC + n)) * NQ + q0) = v;
      }
    }
  } else {
    #pragma unroll
    for (int mi = 0; mi < MI; mi++) {
      int mrow = m0 + mbase + mi * 16 + quad * 4;
      #pragma unroll
      for (int ni = 0; ni < NI; ni++) {
        int n = n0 + nbase + ni * 16 + l16;
        if (n < N) {
          float bv = (EPI == 4) ? 0.f : bias[n];
          #pragma unroll
          for (int r = 0; r < 4; r++) {
            float v = acc[mi][ni][r] + bv;
            if (EPI == 1) {
              v = 0.5f * v * (1.f + erff(v * 0.70710678118654752f));
              outb[(size_t)(mrow + r) * ldo + n] = f2bf(v);
            } else if (EPI == 3) {
              outb[(size_t)(mrow + r) * ldo + n] = f2bf(v);
            } else {
              outf[(size_t)(mrow + r) * ldo + n] = v;
            }
          }
        }
      }
    }
  }
}

// 3-stage pipeline: counted s_waitcnt vmcnt(LPW) + raw s_barrier keeps the
// newest stage's loads in flight ACROSS the barrier. Requires Kloop >= 128.
// LDS: 3*ATILE + 3*BTILE.
template<int BM, int BN, int WM, int WN, int EPI>
__device__ __forceinline__ void gemm_p3(
    const unsigned short* __restrict__ A, const unsigned short* __restrict__ B,
    const float* __restrict__ bias, float* __restrict__ outf,
    unsigned short* __restrict__ outb, int N, int Kloop, int lda, int ldb,
    int ldo, const unsigned short* __restrict__ Zres, float* __restrict__ outT,
    int m0, int n0, unsigned short* As, unsigned short* Bs) {
  constexpr int MI = BM / (WM * 16), NI = BN / (WN * 16);
  constexpr int TA = BM / 8, TB = BN / 8;
  constexpr int LBM = (BM == 32) ? 5 : (BM == 64) ? 6 : 7;
  constexpr int LBN = (BN == 64) ? 6 : (BN == 128) ? 7 : 8;
  constexpr int ATILE = TA * 1024, BTILE = TB * 1024;
  constexpr int LPW = (TA + TB) / 4;
  int tid = threadIdx.x, wave = tid >> 6, lane = tid & 63;
  int quad = lane >> 4, l16 = lane & 15;
  int wm = wave / WN, wn = wave % WN;
  const int mbase = wm * (BM / WM), nbase = wn * (BN / WN);

  ffrag acc[MI][NI];
  #pragma unroll
  for (int i = 0; i < MI; i++)
    #pragma unroll
    for (int j = 0; j < NI; j++) acc[i][j] = (ffrag)0.f;

  auto stage = [&](int kk, int st) {
    for (int t = wave; t < TA + TB; t += 4) {
      if (t < TA) {
        int s = t * 64 + lane;
        int kc = s >> LBM, r = s & (BM - 1);
        gload16(A + (size_t)(m0 + r) * lda + kk + kc * 8,
                (char*)As + st * ATILE + t * 1024);
      } else {
        int s = (t - TA) * 64 + lane;
        int kc = s >> LBN, r = s & (BN - 1);
        gload16(B + (size_t)(n0 + r) * ldb + kk + kc * 8,
                (char*)Bs + st * BTILE + (t - TA) * 1024);
      }
    }
  };

  stage(0, 0);
  stage(64, 1);
  asm volatile("s_waitcnt vmcnt(%0)" :: "n"(LPW) : "memory");
  __builtin_amdgcn_s_barrier();
  asm volatile("" ::: "memory");

  const int nsteps = Kloop >> 6;
  for (int i = 0; i < nsteps; i++) {
    int kn2 = (i + 2) << 6;
    if (kn2 < Kloop) stage(kn2, (i + 2) % 3);
    int bufo = i % 3;
    const unsigned short* Ab = (const unsigned short*)((const char*)As + bufo * ATILE);
    const unsigned short* Bb = (const unsigned short*)((const char*)Bs + bufo * BTILE);
    kstep_mfma<BM, BN, MI, NI, LBM, LBN>(Ab, Bb, quad, l16, mbase, nbase, acc);
    if (i + 1 < nsteps) {
      if (kn2 < Kloop)
        asm volatile("s_waitcnt vmcnt(%0)" :: "n"(LPW) : "memory");
      else
        asm volatile("s_waitcnt vmcnt(0)" ::: "memory");
      __builtin_amdgcn_s_barrier();
      asm volatile("" ::: "memory");
    }
  }
  gemm_epilogue<BM, BN, WM, WN, EPI, MI, NI>(acc, bias, outf, outb, N, ldo,
                                             Zres, outT, m0, n0, quad, l16,
                                             mbase, nbase);
}

// 2-stage dbuf (round-2/4 proven): stage(next) before compute(cur), one
// __syncthreads per K-step. LDS: 2*ATILE + 2*BTILE.
template<int BM, int BN, int WM, int WN, int EPI>
__device__ __forceinline__ void gemm_db2(
    const unsigned short* __restrict__ A, const unsigned short* __restrict__ B,
    const float* __restrict__ bias, float* __restrict__ outf,
    unsigned short* __restrict__ outb, int N, int Kloop, int lda, int ldb,
    int ldo, const unsigned short* __restrict__ Zres, float* __restrict__ outT,
    int m0, int n0, unsigned short* As, unsigned short* Bs) {
  constexpr int MI = BM / (WM * 16), NI = BN / (WN * 16);
  constexpr int TA = BM / 8, TB = BN / 8;
  constexpr int LBM = (BM == 32) ? 5 : (BM == 64) ? 6 : 7;
  constexpr int LBN = (BN == 64) ? 6 : (BN == 128) ? 7 : 8;
  constexpr int ATILE = TA * 1024, BTILE = TB * 1024;
  int tid = threadIdx.x, wave = tid >> 6, lane = tid & 63;
  int quad = lane >> 4, l16 = lane & 15;
  int wm = wave / WN, wn = wave % WN;
  const int mbase = wm * (BM / WM), nbase = wn * (BN / WN);

  ffrag acc[MI][NI];
  #pragma unroll
  for (int i = 0; i < MI; i++)
    #pragma unroll
    for (int j = 0; j < NI; j++) acc[i][j] = (ffrag)0.f;

  auto stage = [&](int kk, int st) {
    for (int t = wave; t < TA + TB; t += 4) {
      if (t < TA) {
        int s = t * 64 + lane;
        int kc = s >> LBM, r = s & (BM - 1);
        gload16(A + (size_t)(m0 + r) * lda + kk + kc * 8,
                (char*)As + st * ATILE + t * 1024);
      } else {
        int s = (t - TA) * 64 + lane;
        int kc = s >> LBN, r = s & (BN - 1);
        gload16(B + (size_t)(n0 + r) * ldb + kk + kc * 8,
                (char*)Bs + st * BTILE + (t - TA) * 1024);
      }
    }
  };

  stage(0, 0);
  __syncthreads();
  int buf = 0;
  for (int k0 = 0; k0 < Kloop; k0 += 64) {
    int kn = k0 + 64;
    if (kn < Kloop) stage(kn, buf ^ 1);
    const unsigned short* Ab = (const unsigned short*)((const char*)As + buf * ATILE);
    const unsigned short* Bb = (const unsigned short*)((const char*)Bs + buf * BTILE);
    kstep_mfma<BM, BN, MI, NI, LBM, LBN>(Ab, Bb, quad, l16, mbase, nbase, acc);
    __syncthreads();
    buf ^= 1;
  }
  gemm_epilogue<BM, BN, WM, WN, EPI, MI, NI>(acc, bias, outf, outb, N, ldo,
                                             Zres, outT, m0, n0, quad, l16,
                                             mbase, nbase);
}

// ================================================================= Q GEMM+LN
// BM=32, BN=256, BK=64. 2-stage dbuf (2x36KB = 72KB sm), single barrier
// per K-step (round-6-verified schedule). LN epilogue reuses sm as fp32 L.
__device__ __forceinline__ void gemm_ln_q(
    const unsigned short* __restrict__ A, const unsigned short* __restrict__ B,
    const float* __restrict__ bias, unsigned short* __restrict__ outb,
    const float* __restrict__ g, const float* __restrict__ be,
    int m0, char* sm) {
  float* L = (float*)sm;
  const int K = 256;

  int tid = threadIdx.x, wave = tid >> 6, lane = tid & 63;
  int quad = lane >> 4, l16 = lane & 15;

  ffrag acc[2][4];
  #pragma unroll
  for (int i = 0; i < 2; i++)
    #pragma unroll
    for (int j = 0; j < 4; j++) acc[i][j] = (ffrag)0.f;

  auto stageq = [&](int k0, int st) {
    char* base = sm + st * 36864;
    for (int t = wave; t < 36; t += 4) {
      if (t < 4) {
        int s = t * 64 + lane;
        int kc = s >> 5, r = s & 31;
        gload16(A + (size_t)(m0 + r) * K + k0 + kc * 8, base + t * 1024);
      } else {
        int s = (t - 4) * 64 + lane;
        int kc = s >> 8, r = s & 255;
        gload16(B + (size_t)r * K + k0 + kc * 8, base + 4096 + (t - 4) * 1024);
      }
    }
  };

  stageq(0, 0);
  __syncthreads();
  for (int i = 0; i < 4; i++) {
    if (i < 3) stageq((i + 1) * 64, (i + 1) & 1);
    const unsigned short* As = (const unsigned short*)(sm + (i & 1) * 36864);
    const unsigned short* Bs = As + 2048;
    #pragma unroll
    for (int ks = 0; ks < 2; ks++) {
      bfrag af[2], bf[4];
      #pragma unroll
      for (int mi = 0; mi < 2; mi++)
        af[mi] = *(const bfrag*)(As + ((((ks * 4 + quad) << 5) + mi * 16 + l16) << 3));
      #pragma unroll
      for (int ni = 0; ni < 4; ni++)
        bf[ni] = *(const bfrag*)(Bs + ((((ks * 4 + quad) << 8) + wave * 64 + ni * 16 + l16) << 3));
      #pragma unroll
      for (int mi = 0; mi < 2; mi++)
        #pragma unroll
        for (int ni = 0; ni < 4; ni++)
          acc[mi][ni] = __builtin_amdgcn_mfma_f32_16x16x32_bf16(
              af[mi], bf[ni], acc[mi][ni], 0, 0, 0);
    }
    __syncthreads();
  }

  #pragma unroll
  for (int mi = 0; mi < 2; mi++) {
    int row = mi * 16 + quad * 4;
    #pragma unroll
    for (int ni = 0; ni < 4; ni++) {
      int col = wave * 64 + ni * 16 + l16;
      float bv = bias[col];
      #pragma unroll
      for (int r = 0; r < 4; r++)
        L[(row + r) * 264 + col] = acc[mi][ni][r] + bv;
    }
  }
  __syncthreads();

  int row = tid >> 3, j = tid & 7;
  int seg = ((j + row) & 7) * 32;
  const float* Lr = L + row * 264 + seg;
  float s1 = 0.f, s2 = 0.f;
  #pragma unroll
  for (int i = 0; i < 8; i++) {
    float4 t4 = *(const float4*)(Lr + i * 4);
    s1 += t4.x + t4.y + t4.z + t4.w;
    s2 += t4.x * t4.x + t4.y * t4.y + t4.z * t4.z + t4.w * t4.w;
  }
  #pragma unroll
  for (int o = 1; o < 8; o <<= 1) {
    s1 += __shfl_xor(s1, o);
    s2 += __shfl_xor(s2, o);
  }
  float mu = s1 * (1.f / 256.f);
  float var = s2 * (1.f / 256.f) - mu * mu;
  float rs = rsqrtf(var + 1e-5f);
  int gm = m0 + row;
  #pragma unroll
  for (int i = 0; i < 8; i++) {
    int col = seg + i * 4;
    float4 t4 = *(const float4*)(Lr + i * 4);
    float4 gg = *(const float4*)(g + col);
    float4 bb4 = *(const float4*)(be + col);
    ushort4 ub;
    ub.x = f2bf((t4.x - mu) * rs * gg.x + bb4.x);
    ub.y = f2bf((t4.y - mu) * rs * gg.y + bb4.y);
    ub.z = f2bf((t4.z - mu) * rs * gg.z + bb4.z);
    ub.w = f2bf((t4.w - mu) * rs * gg.w + bb4.w);
    *(ushort4*)(outb + (size_t)gm * CC + col) = ub;
  }
}

// ================================================================= kernels
// qv: [0,256) Q-LN dbuf | [256,512) V0 p3 | [512,640) V1 split2 p3
//     [640,704) V2 split4 p3 — m-fastest tile order (XCD-disjoint A-slabs)
__global__ __launch_bounds__(256)
void qv_k(const unsigned short* Sbf, const unsigned short* q_wb, const float* q_b,
          const float* lnq_g, const float* lnq_b, unsigned short* Qbf,
          const unsigned short* Xf0, const unsigned short* Xf1,
          const unsigned short* Xf2, const unsigned short* vw0b,
          const unsigned short* vw1b, const unsigned short* vw2b,
          const float* vb0, unsigned short* V0b, float* Vp1, float* Vp2) {
  __shared__ __attribute__((aligned(16))) char sm[73728];
  int bid = blockIdx.x;
  unsigned short* As = (unsigned short*)sm;
  unsigned short* Bs = (unsigned short*)(sm + 24576);
  if (bid < 256) {
    gemm_ln_q(Sbf, q_wb, q_b, Qbf, lnq_g, lnq_b, bid * 32, sm);
  } else if (bid < 512) {
    int t = bid - 256;
    gemm_p3<64, 128, 2, 2, 3>(Xf0, vw0b, vb0, nullptr, V0b, 256, 256, 256,
                              256, 256, nullptr, nullptr,
                              (t & 127) * 64, (t >> 7) * 128, As, Bs);
  } else if (bid < 640) {
    int l = bid - 512, ks = l >> 6, t = l & 63;
    gemm_p3<64, 128, 2, 2, 4>(Xf1 + ks * 256, vw1b + ks * 256, nullptr,
                              Vp1 + (size_t)ks * 524288, nullptr, 256, 256,
                              512, 512, 256, nullptr, nullptr,
                              (t & 31) * 64, (t >> 5) * 128, As, Bs);
  } else {
    int l = bid - 640, ks = l >> 4, t = l & 15;
    gemm_p3<64, 128, 2, 2, 4>(Xf2 + ks * 256, vw2b + ks * 256, nullptr,
                              Vp2 + (size_t)ks * 131072, nullptr, 256, 256,
                              1024, 1024, 256, nullptr, nullptr,
                              (t & 7) * 64, (t >> 3) * 128, As, Bs);
  }
}

// offv: [0,256) offwgt GEMM 64x128 p3, m-fastest | [256,768) V1 red | [768,896) V2 red
__global__ __launch_bounds__(256)
void offv_k(const unsigned short* Qbf, const unsigned short* owb,
            const float* bias144, float* offwgt,
            const float* Vp1, const float* Vp2, const float* vb1,
            const float* vb2, unsigned short* V1b, unsigned short* V2b) {
  __shared__ __attribute__((aligned(16))) char sm[73728];
  int bid = blockIdx.x;
  if (bid < 256) {
    unsigned short* As = (unsigned short*)sm;
    unsigned short* Bs = (unsigned short*)(sm + 24576);
    gemm_p3<64, 128, 2, 2, 0>(Qbf, owb, bias144, offwgt, nullptr, 144, 256,
                              256, 256, 144, nullptr, nullptr,
                              (bid & 127) * 64, (bid >> 7) * 128, As, Bs);
  } else if (bid < 768) {
    int e4 = (bid - 256) * 256 + threadIdx.x;
    const float4* P = (const float4*)Vp1;
    float4 a = P[e4], b = P[e4 + 131072];
    float4 bb = *(const float4*)(vb1 + ((e4 << 2) & 255));
    ushort4 u;
    u.x = f2bf(a.x + b.x + bb.x); u.y = f2bf(a.y + b.y + bb.y);
    u.z = f2bf(a.z + b.z + bb.z); u.w = f2bf(a.w + b.w + bb.w);
    ((ushort4*)V1b)[e4] = u;
  } else {
    int e4 = (bid - 768) * 256 + threadIdx.x;
    const float4* P = (const float4*)Vp2;
    float4 a = P[e4], b = P[e4 + 32768], c = P[e4 + 65536], d = P[e4 + 98304];
    float4 bb = *(const float4*)(vb2 + ((e4 << 2) & 255));
    ushort4 u;
    u.x = f2bf(a.x + b.x + c.x + d.x + bb.x);
    u.y = f2bf(a.y + b.y + c.y + d.y + bb.y);
    u.z = f2bf(a.z + b.z + c.z + d.z + bb.z);
    u.w = f2bf(a.w + b.w + c.w + d.w + bb.w);
    ((ushort4*)V2b)[e4] = u;
  }
}

// outA: split-K=2, 128x128 db2 tiles, grid (m=64, n=2, ks=2) = 256 blocks
__global__ __launch_bounds__(256)
void outA_k(const unsigned short* accbf, const unsigned short* out_wb, float* Op) {
  __shared__ __attribute__((aligned(16))) char sm[65536];
  int ks = blockIdx.z;
  gemm_db2<128, 128, 2, 2, 4>(accbf + ks * 512, out_wb + ks * 512, nullptr,
                              Op + (size_t)ks * 2097152, nullptr, 256, 512,
                              1024, 1024, 256, nullptr, nullptr,
                              blockIdx.x * 128, blockIdx.y * 128,
                              (unsigned short*)sm, (unsigned short*)(sm + 32768));
}

// outB: reduce 2 partials + bias + S residual + LN -> Zbf bf16
__global__ __launch_bounds__(256)
void outB_k(const float* __restrict__ Op, const float* __restrict__ S,
            const float* __restrict__ out_b, const float* __restrict__ g,
            const float* __restrict__ be, unsigned short* __restrict__ Zbf) {
  __shared__ float Ls[16][264];
  int q0 = blockIdx.x * 16;
  int b = q0 >> 12, qq = q0 & (NQ - 1);
  int t = threadIdx.x;
  {
    int cs = t >> 2, j = (t & 3) * 4;
    #pragma unroll
    for (int c0 = 0; c0 < 256; c0 += 64) {
      float4 sv = *(const float4*)(S + (((size_t)(b * 256 + c0 + cs)) << 12) + qq + j);
      Ls[j + 0][c0 + cs] = sv.x; Ls[j + 1][c0 + cs] = sv.y;
      Ls[j + 2][c0 + cs] = sv.z; Ls[j + 3][c0 + cs] = sv.w;
    }
  }
  __syncthreads();
  int c = t;
  float bv = out_b[c];
  float val[16];
  #pragma unroll
  for (int r = 0; r < 16; r++) {
    size_t idx = (size_t)(q0 + r) * 256 + c;
    val[r] = Op[idx] + Op[idx + 2097152] + bv + Ls[r][c];
  }
  __syncthreads();
  #pragma unroll
  for (int r = 0; r < 16; r++) Ls[r][c] = val[r];
  __syncthreads();
  int row = t >> 4, lg = t & 15;
  const float* Lr = &Ls[row][lg * 16];
  float s1 = 0.f, s2 = 0.f;
  #pragma unroll
  for (int i = 0; i < 4; i++) {
    float4 t4 = *(const float4*)(Lr + i * 4);
    s1 += t4.x + t4.y + t4.z + t4.w;
    s2 += t4.x * t4.x + t4.y * t4.y + t4.z * t4.z + t4.w * t4.w;
  }
  #pragma unroll
  for (int o = 1; o < 16; o <<= 1) {
    s1 += __shfl_xor(s1, o);
    s2 += __shfl_xor(s2, o);
  }
  float mu = s1 * (1.f / 256.f);
  float var = s2 * (1.f / 256.f) - mu * mu;
  float rs = rsqrtf(var + 1e-5f);
  int gm = q0 + row;
  #pragma unroll
  for (int i = 0; i < 4; i++) {
    int col = lg * 16 + i * 4;
    float4 t4 = *(const float4*)(Lr + i * 4);
    float4 gg = *(const float4*)(g + col);
    float4 bb4 = *(const float4*)(be + col);
    ushort4 ub;
    ub.x = f2bf((t4.x - mu) * rs * gg.x + bb4.x);
    ub.y = f2bf((t4.y - mu) * rs * gg.y + bb4.y);
    ub.z = f2bf((t4.z - mu) * rs * gg.z + bb4.z);
    ub.w = f2bf((t4.w - mu) * rs * gg.w + bb4.w);
    *(ushort4*)(Zbf + (size_t)gm * CC + col) = ub;
  }
}

// fc1: 128x128 db2 tiles (2:1 MFMA:ds_read), grid (m=64, n=8) m-fastest
__global__ __launch_bounds__(256)
void fc1_k(const unsigned short* Zbf, const unsigned short* fc1_wb,
           const float* fc1_b, unsigned short* hbf) {
  __shared__ __attribute__((aligned(16))) char sm[65536];
  gemm_db2<128, 128, 2, 2, 1>(Zbf, fc1_wb, fc1_b, nullptr, hbf, 1024, 256,
                              256, 256, 1024, nullptr, nullptr,
                              blockIdx.x * 128, blockIdx.y * 128,
                              (unsigned short*)sm, (unsigned short*)(sm + 32768));
}

// fc2: full-K=1024, 64x64 p3 tile, grid (m=128, n=4) m-fastest
__global__ __launch_bounds__(256)
void fc2_k(const unsigned short* hbf, const unsigned short* fc2_wb,
           const float* fc2_b, const unsigned short* Zbf, float* outp) {
  __shared__ __attribute__((aligned(16))) char sm[49152];
  gemm_p3<64, 64, 2, 2, 2>(hbf, fc2_wb, fc2_b, nullptr, nullptr, 256, 1024,
                           1024, 1024, 256, Zbf, outp,
                           blockIdx.x * 64, blockIdx.y * 64,
                           (unsigned short*)sm, (unsigned short*)(sm + 24576));
}

// ================================================================= sampling
__global__ __launch_bounds__(256)
void sample_k(const float* __restrict__ ow, const float* __restrict__ sim,
              const unsigned short* __restrict__ V0, const unsigned short* __restrict__ V1,
              const unsigned short* __restrict__ V2, unsigned short* __restrict__ acc) {
  int bn = blockIdx.x;
  int q = ((bn & 7) << 10) | (bn >> 3);
  int b = q >> 12, n = q & (NQ - 1);
  int tid = threadIdx.x, head = tid >> 6, lane = tid & 63;
  int half = lane >> 5, l32 = lane & 31;

  __shared__ float s_w[48];
  __shared__ int   s_xy[48][2];
  __shared__ float s_f[48][2];
  __shared__ uint2 s_ow[192];

  if (tid < 48) {
    int hh = tid / 12, pt = tid % 12, l = pt >> 2, mm = pt & 3;
    int oidx = (hh * 3 + l) * 4 + mm;
    float offx = ow[(size_t)q * 144 + oidx * 2 + 0];
    float offy = ow[(size_t)q * 144 + oidx * 2 + 1];
    float refx = ((n & 63) + 0.5f) * (1.f / 64.f);
    float refy = ((n >> 6) + 0.5f) * (1.f / 64.f);
    float gx = tanhf((refx + offx) * 2.f - 1.f);
    float gy = tanhf((refy + offy) * 2.f - 1.f);
    gx = fminf(1.f, fmaxf(-1.f, gx));
    gy = fminf(1.f, fmaxf(-1.f, gy));
    int Wl = 64 >> l;
    float x = (gx + 1.f) * 0.5f * (float)(Wl - 1);
    float y = (gy + 1.f) * 0.5f * (float)(Wl - 1);
    float x0 = floorf(x), y0 = floorf(y);
    s_xy[tid][0] = (int)x0;
    s_xy[tid][1] = (int)y0;
    s_f[tid][0] = x - x0;
    s_f[tid][1] = y - y0;
    s_w[tid] = ow[(size_t)q * 144 + 96 + oidx] * (sim[q] + 0.001f);
  }
  __syncthreads();
  if (tid < 4) {
    float mx = -1e30f;
    #pragma unroll
    for (int i = 0; i < 12; i++) mx = fmaxf(mx, s_w[tid * 12 + i]);
    float e[12], ssum = 0.f;
    #pragma unroll
    for (int i = 0; i < 12; i++) { e[i] = expf(s_w[tid * 12 + i] - mx); ssum += e[i]; }
    float inv = 1.f / ssum;
    #pragma unroll
    for (int i = 0; i < 12; i++) s_w[tid * 12 + i] = e[i] * inv;
  }
  __syncthreads();
  if (tid < 192) {
    int s = tid >> 2, tap = tid & 3;
    int l = (s % 12) >> 2;
    int Wl = 64 >> l;
    int X = s_xy[s][0] + (tap & 1), Y = s_xy[s][1] + (tap >> 1);
    bool valid = (X >= 0 && X < Wl && Y >= 0 && Y < Wl);
    float wx = (tap & 1) ? s_f[s][0] : 1.f - s_f[s][0];
    float wy = (tap >> 1) ? s_f[s][1] : 1.f - s_f[s][1];
    float twt = valid ? s_w[s] * wx * wy : 0.f;
    int Xc = min(max(X, 0), Wl - 1), Yc = min(max(Y, 0), Wl - 1);
    s_ow[tid].x = (unsigned)((Yc * Wl + Xc) << 8);
    s_ow[tid].y = __float_as_uint(twt);
  }
  __syncthreads();

  const unsigned short* B0 = V0 + (size_t)b * 4096 * CC;
  const unsigned short* B1 = V1 + (size_t)b * 1024 * CC;
  const unsigned short* B2 = V2 + (size_t)b * 256 * CC;
  int ch8 = l32 * 8;
  float a0 = 0.f, a1 = 0.f, a2 = 0.f, a3 = 0.f;
  float a4 = 0.f, a5 = 0.f, a6 = 0.f, a7 = 0.f;
  #pragma unroll
  for (int it = 0; it < 24; it++) {
    const unsigned short* base = (it < 8) ? B0 : (it < 16) ? B1 : B2;
    uint2 owv = s_ow[head * 48 + it * 2 + half];
    float w = __uint_as_float(owv.y);
    const uint4 u = *(const uint4*)(base + owv.x + ch8);
    a0 = fmaf(w, __uint_as_float(u.x << 16), a0);
    a1 = fmaf(w, __uint_as_float(u.x & 0xffff0000u), a1);
    a2 = fmaf(w, __uint_as_float(u.y << 16), a2);
    a3 = fmaf(w, __uint_as_float(u.y & 0xffff0000u), a3);
    a4 = fmaf(w, __uint_as_float(u.z << 16), a4);
    a5 = fmaf(w, __uint_as_float(u.z & 0xffff0000u), a5);
    a6 = fmaf(w, __uint_as_float(u.w << 16), a6);
    a7 = fmaf(w, __uint_as_float(u.w & 0xffff0000u), a7);
  }
  a0 += __shfl_xor(a0, 32); a1 += __shfl_xor(a1, 32);
  a2 += __shfl_xor(a2, 32); a3 += __shfl_xor(a3, 32);
  a4 += __shfl_xor(a4, 32); a5 += __shfl_xor(a5, 32);
  a6 += __shfl_xor(a6, 32); a7 += __shfl_xor(a7, 32);
  if (half == 0) {
    uint4 r;
    r.x = (unsigned)f2bf(a0) | ((unsigned)f2bf(a1) << 16);
    r.y = (unsigned)f2bf(a2) | ((unsigned)f2bf(a3) << 16);
    r.z = (unsigned)f2bf(a4) | ((unsigned)f2bf(a5) << 16);
    r.w = (unsigned)f2bf(a6) | ((unsigned)f2bf(a7) << 16);
    *(uint4*)(acc + (size_t)q * 1024 + head * CC + ch8) = r;
  }
}

// ================================================================= launch
extern "C" void kernel_launch(void* const* d_in, const int* in_sizes, int n_in,
                              void* d_out, int out_size, void* d_ws, size_t ws_size,
                              hipStream_t stream) {
  const float* S     = (const float*)d_in[0];
  const float* f0    = (const float*)d_in[1];
  const float* f1    = (const float*)d_in[2];
  const float* f2    = (const float*)d_in[3];
  const float* sim   = (const float*)d_in[4];
  const float* vw0   = (const float*)d_in[5];
  const float* vb0   = (const float*)d_in[6];
  const float* vw1   = (const float*)d_in[7];
  const float* vb1   = (const float*)d_in[8];
  const float* vw2   = (const float*)d_in[9];
  const float* vb2   = (const float*)d_in[10];
  const float* q_w   = (const float*)d_in[11];
  const float* q_b   = (const float*)d_in[12];
  const float* off_w = (const float*)d_in[13];
  const float* off_b = (const float*)d_in[14];
  const float* wgt_w = (const float*)d_in[15];
  const float* wgt_b = (const float*)d_in[16];
  const float* out_w = (const float*)d_in[17];
  const float* out_b = (const float*)d_in[18];
  const float* lnq_g = (const float*)d_in[19];
  const float* lnq_b = (const float*)d_in[20];
  const float* lno_g = (const float*)d_in[21];
  const float* lno_b = (const float*)d_in[22];
  const float* fc1_w = (const float*)d_in[23];
  const float* fc1_b = (const float*)d_in[24];
  const float* fc2_w = (const float*)d_in[25];
  const float* fc2_b = (const float*)d_in[26];

  char* p = (char*)d_ws;
  float* offwgt = (float*)p; p += 4718592;
  float* bias144 = (float*)p; p += 1024;
  float* Pp     = (float*)p; p += 16777216;   // outA partials (2 slices)
  float* Vp1    = (float*)p; p += 4194304;
  float* Vp2    = (float*)p; p += 2097152;
  unsigned short* Sbf   = (unsigned short*)p; p += 4194304;
  unsigned short* Qbf   = (unsigned short*)p; p += 4194304;   // alias Zbf
  unsigned short* accbf = (unsigned short*)p; p += 16777216;  // alias Xf*, hbf
  unsigned short* V0b   = (unsigned short*)p; p += 4194304;
  unsigned short* V1b   = (unsigned short*)p; p += 1048576;
  unsigned short* V2b   = (unsigned short*)p; p += 262144;
  unsigned short* q_wb   = (unsigned short*)p; p += 131072;
  unsigned short* owb    = (unsigned short*)p; p += 131072;
  unsigned short* vw0b   = (unsigned short*)p; p += 131072;
  unsigned short* vw1b   = (unsigned short*)p; p += 262144;
  unsigned short* vw2b   = (unsigned short*)p; p += 524288;
  unsigned short* out_wb = (unsigned short*)p; p += 524288;
  unsigned short* fc1_wb = (unsigned short*)p; p += 524288;
  unsigned short* fc2_wb = (unsigned short*)p; p += 524288;

  unsigned short* Xf0 = accbf;
  unsigned short* Xf1 = accbf + 2097152;
  unsigned short* Xf2 = accbf + 3145728;
  unsigned short* Zbf = Qbf;
  unsigned short* hbf = accbf;
  float* outp = (float*)d_out;

  prep_all_k<<<2944, 256, 0, stream>>>(S, f0, f1, f2, q_w, off_w, wgt_w,
      vw0, vw1, vw2, out_w, fc1_w, fc2_w, off_b, wgt_b,
      Sbf, Xf0, Xf1, Xf2, q_wb, owb, vw0b, vw1b, vw2b, out_wb,
      fc1_wb, fc2_wb, bias144);

  qv_k<<<704, 256, 0, stream>>>(Sbf, q_wb, q_b, lnq_g, lnq_b, Qbf,
      Xf0, Xf1, Xf2, vw0b, vw1b, vw2b, vb0, V0b, Vp1, Vp2);

  offv_k<<<896, 256, 0, stream>>>(Qbf, owb, bias144, offwgt,
      Vp1, Vp2, vb1, vb2, V1b, V2b);

  sample_k<<<8192, 256, 0, stream>>>(offwgt, sim, V0b, V1b, V2b, accbf);

  outA_k<<<dim3(64, 2, 2), 256, 0, stream>>>(accbf, out_wb, Pp);

  outB_k<<<512, 256, 0, stream>>>(Pp, S, out_b, lno_g, lno_b, Zbf);

  fc1_k<<<dim3(64, 8), 256, 0, stream>>>(Zbf, fc1_wb, fc1_b, hbf);

  fc2_k<<<dim3(128, 4), 256, 0, stream>>>(hbf, fc2_wb, fc2_b, Zbf, outp);
}